// Round 11
// baseline (272.881 us; speedup 1.0000x reference)
//
#include <hip/hip_runtime.h>
#include <hip/hip_bf16.h>

#define BATCH 8
#define NNODE 2048
#define FDIM 256
#define HD 256
#define NH 4
#define MROWS (BATCH*NNODE)

typedef float f32x4 __attribute__((ext_vector_type(4)));
typedef short s16x8 __attribute__((ext_vector_type(8)));
typedef unsigned short ushort_t;

#define MFMA __builtin_amdgcn_mfma_f32_16x16x32_bf16
#define SCHED0() __builtin_amdgcn_sched_barrier(0)
#define SBAR() __builtin_amdgcn_s_barrier()

// RNE round to bf16
__device__ __forceinline__ ushort_t f2bf(float f) {
    unsigned u = __builtin_bit_cast(unsigned, f);
    u += 0x7fffu + ((u >> 16) & 1u);
    return (ushort_t)(u >> 16);
}
// truncation hi/lo split: f = hi + lo + eps, |eps| <= 2^-16 |f|
__device__ __forceinline__ void split2(float f, ushort_t& h, ushort_t& l) {
    unsigned u = __builtin_bit_cast(unsigned, f);
    h = (ushort_t)(u >> 16);
    float fh = __builtin_bit_cast(float, u & 0xffff0000u);
    float lo = f - fh;                       // exact
    l = (ushort_t)(__builtin_bit_cast(unsigned, lo) >> 16);
}

// global -> LDS direct (wave-uniform LDS base + lane*16; per-lane global src)
#define GLOAD16(gp, lp) __builtin_amdgcn_global_load_lds( \
    (const __attribute__((address_space(1))) void*)(gp),  \
    (__attribute__((address_space(3))) void*)(lp), 16, 0, 0)

// ---------------------------------------------------------------------------
// wprep: wt_hi/lo[n][k] = trunc-split(W[k][n])  (gemm1's B stays split: e needs it)
// ---------------------------------------------------------------------------
__global__ __launch_bounds__(256) void wprep_kernel(
    const float* __restrict__ Wm,
    ushort_t* __restrict__ wt_hi, ushort_t* __restrict__ wt_lo)
{
    const int nn = blockIdx.x, k = threadIdx.x;
    ushort_t h, l;
    split2(Wm[(size_t)k * HD + nn], h, l);
    wt_hi[nn * FDIM + k] = h;
    wt_lo[nn * FDIM + k] = l;
}

// ---------------------------------------------------------------------------
// GEMM1: Wh = features @ W. 64x64 tiles, BK=64, K=256 (4 tiles).
// grid (256, 4); 4 waves 2x2; wave tile 32x32. Emits WhT_hi (RNE) + e (fp32).
// (unchanged from R9)
// ---------------------------------------------------------------------------
__global__ __launch_bounds__(256, 4) void gemm1_kernel(
    const float* __restrict__ features,
    const ushort_t* __restrict__ wt_hi,
    const ushort_t* __restrict__ wt_lo,
    ushort_t* __restrict__ WhT_hi,
    float* __restrict__ e_out)
{
    __shared__ __align__(16) ushort_t Ah[64 * 64];
    __shared__ __align__(16) ushort_t Al[64 * 64];
    __shared__ __align__(16) ushort_t Bh[64 * 64];
    __shared__ __align__(16) ushort_t Bl[64 * 64];
    __shared__ float red[64][2];

    const int tid = threadIdx.x, lane = tid & 63, w = tid >> 6;
    const int wr = w >> 1, wc = w & 1;
    const int row0 = blockIdx.x * 64;
    const int head = blockIdx.y;
    const int col0 = head * 64;

    const float* Ab = features + (size_t)row0 * FDIM;
    const ushort_t* Bhg = wt_hi + (size_t)col0 * FDIM;
    const ushort_t* Blg = wt_lo + (size_t)col0 * FDIM;

    const int sr0 = tid >> 3;
    const int sg8 = tid & 7;
    const int bc = (lane >> 3);
    const int bs = lane & 7;

    f32x4 ar[4];
    f32x4 acc[2][2];
    #pragma unroll
    for (int m = 0; m < 2; ++m)
        #pragma unroll
        for (int n = 0; n < 2; ++n) acc[m][n] = (f32x4)0.f;

    #define G1_LOADA(K0) do {                                                  \
        _Pragma("unroll")                                                      \
        for (int i = 0; i < 2; ++i) {                                          \
            const int r = sr0 + 32 * i;                                        \
            ar[2*i]   = *(const f32x4*)&Ab[(size_t)r * FDIM + (K0) + sg8 * 8]; \
            ar[2*i+1] = *(const f32x4*)&Ab[(size_t)r * FDIM + (K0) + sg8 * 8 + 4]; \
        }                                                                      \
    } while (0)

    #define G1_STAGEA() do {                                                   \
        _Pragma("unroll")                                                      \
        for (int i = 0; i < 2; ++i) {                                          \
            const int r = sr0 + 32 * i;                                        \
            s16x8 vh, vl; ushort_t hh, ll;                                     \
            _Pragma("unroll")                                                  \
            for (int j = 0; j < 4; ++j) {                                      \
                split2(ar[2*i][j], hh, ll);  vh[j] = (short)hh; vl[j] = (short)ll; \
            }                                                                  \
            _Pragma("unroll")                                                  \
            for (int j = 0; j < 4; ++j) {                                      \
                split2(ar[2*i+1][j], hh, ll); vh[4+j] = (short)hh; vl[4+j] = (short)ll; \
            }                                                                  \
            const int off = r * 64 + ((sg8 ^ (r & 7)) << 3);                   \
            *(s16x8*)&Ah[off] = vh; *(s16x8*)&Al[off] = vl;                    \
        }                                                                      \
    } while (0)

    #define G1_STAGEB(K0) do {                                                 \
        _Pragma("unroll")                                                      \
        for (int qq = 0; qq < 2; ++qq) {                                       \
            const int q = w + qq * 4;                                          \
            const int c = q * 8 + bc;                                          \
            const int g = bs ^ (c & 7);                                        \
            GLOAD16(&Bhg[(size_t)c * FDIM + (K0) + g * 8], &Bh[q * 512]);      \
            GLOAD16(&Blg[(size_t)c * FDIM + (K0) + g * 8], &Bl[q * 512]);      \
        }                                                                      \
    } while (0)

    G1_LOADA(0);
    for (int t = 0; t < 4; ++t) {
        G1_STAGEB(t * 64);
        G1_STAGEA();
        if (t < 3) G1_LOADA((t + 1) * 64);
        if (t < 3) { asm volatile("s_waitcnt lgkmcnt(0) vmcnt(4)" ::: "memory"); }
        else       { asm volatile("s_waitcnt lgkmcnt(0) vmcnt(0)" ::: "memory"); }
        SCHED0(); SBAR(); SCHED0();
        #pragma unroll
        for (int kh = 0; kh < 2; ++kh) {
            const int kg = kh * 4 + (lane >> 4);
            s16x8 afh[2], afl[2], bfh[2], bfl[2];
            #pragma unroll
            for (int m = 0; m < 2; ++m) {
                const int r = wr * 32 + m * 16 + (lane & 15);
                const int off = r * 64 + ((kg ^ (r & 7)) << 3);
                afh[m] = *(const s16x8*)&Ah[off];
                afl[m] = *(const s16x8*)&Al[off];
            }
            #pragma unroll
            for (int n = 0; n < 2; ++n) {
                const int c = wc * 32 + n * 16 + (lane & 15);
                const int off = c * 64 + ((kg ^ (c & 7)) << 3);
                bfh[n] = *(const s16x8*)&Bh[off];
                bfl[n] = *(const s16x8*)&Bl[off];
            }
            #pragma unroll
            for (int m = 0; m < 2; ++m)
                #pragma unroll
                for (int n = 0; n < 2; ++n) {
                    acc[m][n] = MFMA(afh[m], bfh[n], acc[m][n], 0, 0, 0);
                    acc[m][n] = MFMA(afh[m], bfl[n], acc[m][n], 0, 0, 0);
                    acc[m][n] = MFMA(afl[m], bfh[n], acc[m][n], 0, 0, 0);
                }
        }
        SCHED0(); SBAR(); SCHED0();
    }

    // ---- e: row sums of squares (64 cols of this head), fp32
    #pragma unroll
    for (int m = 0; m < 2; ++m)
        #pragma unroll
        for (int j = 0; j < 4; ++j) {
            float p = acc[m][0][j] * acc[m][0][j] + acc[m][1][j] * acc[m][1][j];
            p += __shfl_xor(p, 1, 64);
            p += __shfl_xor(p, 2, 64);
            p += __shfl_xor(p, 4, 64);
            p += __shfl_xor(p, 8, 64);
            if ((lane & 15) == 0)
                red[wr * 32 + m * 16 + (lane >> 4) * 4 + j][wc] = p;
        }

    // ---- WhT (RNE bf16) via LDS transpose
    __syncthreads();
    ushort_t* Th = Ah;
    #pragma unroll
    for (int m = 0; m < 2; ++m)
        #pragma unroll
        for (int n = 0; n < 2; ++n)
            #pragma unroll
            for (int j = 0; j < 4; ++j) {
                const int rr = wr * 32 + m * 16 + (lane >> 4) * 4 + j;
                const int cc = wc * 32 + n * 16 + (lane & 15);
                const int ad = cc * 64 + ((((rr >> 3) ^ (cc & 7))) << 3) + (rr & 7);
                Th[ad] = f2bf(acc[m][n][j]);
            }
    __syncthreads();

    if (tid < 64) {
        const int rg = row0 + tid;
        e_out[((size_t)((rg >> 11) * NH + head)) * NNODE + (rg & 2047)] =
            red[tid][0] + red[tid][1];
    }
    const int bb = row0 >> 11, node0 = row0 & 2047;
    #pragma unroll
    for (int i = 0; i < 2; ++i) {
        const int g2 = tid + 256 * i;
        const int c = g2 >> 3, gr = g2 & 7;
        const int ad = c * 64 + ((gr ^ (c & 7)) << 3);
        uint4 vh = *(const uint4*)&Th[ad];
        const size_t o = ((size_t)bb * HD + col0 + c) * NNODE + node0 + gr * 8;
        *(uint4*)&WhT_hi[o] = vh;
    }
}

// ---------------------------------------------------------------------------
// softmax stats: ms[bh*2] = max, ms[bh*2+1] = 1/sum
// ---------------------------------------------------------------------------
__global__ __launch_bounds__(256) void sm_kernel(
    const float* __restrict__ e, float* __restrict__ ms)
{
    __shared__ float red[8];
    const int bh = blockIdx.x, tid = threadIdx.x;
    const int lane = tid & 63, w = tid >> 6;
    const float* row = e + (size_t)bh * NNODE;
    float mx = -3.0e38f;
    for (int n = tid; n < NNODE; n += 256) mx = fmaxf(mx, row[n]);
    #pragma unroll
    for (int off = 32; off; off >>= 1) mx = fmaxf(mx, __shfl_xor(mx, off, 64));
    if (lane == 0) red[w] = mx;
    __syncthreads();
    mx = fmaxf(fmaxf(red[0], red[1]), fmaxf(red[2], red[3]));
    float s = 0.f;
    for (int n = tid; n < NNODE; n += 256) s += expf(row[n] - mx);
    #pragma unroll
    for (int off = 32; off; off >>= 1) s += __shfl_xor(s, off, 64);
    if (lane == 0) red[4 + w] = s;
    __syncthreads();
    if (tid == 0) {
        ms[bh * 2] = mx;
        ms[bh * 2 + 1] = 1.0f / (red[4] + red[5] + red[6] + red[7]);
    }
}

// ---------------------------------------------------------------------------
// GEMM2: out = relu(att[row]*(adj @ Wh) + bias), att in epilogue.
// 128x64 tiles, BK=64, grid 512 XCD-swizzled. ZERO barriers: each wave
// stages the whole 64x64 B-tile into its OWN LDS double-buffer and free-runs
// with counted vmcnt. Phase order is PINNED with sched_barrier(0) so the
// vmcnt queue arithmetic holds (R10 failed because the scheduler reordered
// plain A-loads vs global_load_lds, breaking the count).
// ---------------------------------------------------------------------------
__global__ __launch_bounds__(256, 2) void gemm2_kernel(
    const float* __restrict__ adj,
    const ushort_t* __restrict__ WhT_hi,
    const float* __restrict__ e,
    const float* __restrict__ ms,
    const float* __restrict__ bias,
    float* __restrict__ out)
{
    __shared__ __align__(16) ushort_t Bh[4][2][64 * 64];   // [wave][buf] 64 KB

    const int tid = threadIdx.x, lane = tid & 63, w = tid >> 6;

    // XCD-chunked swizzle (512 = 8 XCD x 64): XCD n owns batch n entirely.
    const int bid = blockIdx.x;
    const int wg = (bid & 7) * 64 + (bid >> 3);
    const int bx = wg & 15, by = (wg >> 4) & 3, b = wg >> 6;
    const int row0 = bx * 128, col0 = by * 64;

    const ushort_t* Bhg = WhT_hi + ((size_t)b * HD + col0) * NNODE;
    const float* pA = adj + (size_t)b * NNODE * NNODE
                    + (size_t)(row0 + w * 32 + (lane & 15)) * NNODE
                    + ((lane >> 4) * 8);

    // wave-private B staging: instr i covers cols [i*8, i*8+8)
    const int scol = lane >> 3;          // col-in-group
    const int sgr  = (lane & 7) ^ scol;  // swizzled source granule (c&7 == scol)
    ushort_t* myB0 = &Bh[w][0][0];
    ushort_t* myB1 = &Bh[w][1][0];

    f32x4 arE[8], arO[8];       // [m*4 + ks*2 + half], even/odd tile A sets
    s16x8 afh[2][2];            // converted A frags [m][ks]
    f32x4 acc[2][4];
    #pragma unroll
    for (int m = 0; m < 2; ++m)
        #pragma unroll
        for (int n = 0; n < 4; ++n) acc[m][n] = (f32x4)0.f;

    #define G2_LOADA(AR, K0) do {                                               \
        _Pragma("unroll")                                                       \
        for (int m = 0; m < 2; ++m)                                             \
        _Pragma("unroll")                                                       \
        for (int ks = 0; ks < 2; ++ks) {                                        \
            AR[m*4+ks*2+0] = *(const f32x4*)&pA[(size_t)m * 16 * NNODE + (K0) + ks * 32]; \
            AR[m*4+ks*2+1] = *(const f32x4*)&pA[(size_t)m * 16 * NNODE + (K0) + ks * 32 + 4]; \
        }                                                                       \
    } while (0)

    #define G2_CONVERT(AR) do {                                                 \
        _Pragma("unroll")                                                       \
        for (int m = 0; m < 2; ++m)                                             \
        _Pragma("unroll")                                                       \
        for (int ks = 0; ks < 2; ++ks)                                          \
        _Pragma("unroll")                                                       \
        for (int h2 = 0; h2 < 2; ++h2)                                          \
        _Pragma("unroll")                                                       \
        for (int j = 0; j < 4; ++j)                                             \
            afh[m][ks][h2 * 4 + j] = (short)f2bf(AR[m*4+ks*2+h2][j]);           \
    } while (0)

    // whole 64x64 B tile, wave-private: 8 gload_lds of 1 KB
    #define G2_STAGEB(LB, K0) do {                                              \
        _Pragma("unroll")                                                       \
        for (int i = 0; i < 8; ++i) {                                           \
            const int c = i * 8 + scol;                                         \
            GLOAD16(&Bhg[(size_t)c * NNODE + (K0) + sgr * 8], (LB) + i * 512);  \
        }                                                                       \
    } while (0)

    #define G2_COMPUTE(LB) do {                                                 \
        _Pragma("unroll")                                                       \
        for (int ks = 0; ks < 2; ++ks) {                                        \
            const int kg = ks * 4 + (lane >> 4);                                \
            s16x8 bfh[4];                                                       \
            _Pragma("unroll")                                                   \
            for (int n = 0; n < 4; ++n) {                                       \
                const int c = n * 16 + (lane & 15);                             \
                const int off = c * 64 + ((kg ^ (c & 7)) << 3);                 \
                bfh[n] = *(const s16x8*)&(LB)[off];                             \
            }                                                                   \
            __builtin_amdgcn_s_setprio(1);                                      \
            _Pragma("unroll")                                                   \
            for (int m = 0; m < 2; ++m)                                         \
            _Pragma("unroll")                                                   \
            for (int n = 0; n < 4; ++n)                                         \
                acc[m][n] = MFMA(afh[m][ks], bfh[n], acc[m][n], 0, 0, 0);       \
            __builtin_amdgcn_s_setprio(0);                                      \
        }                                                                       \
    } while (0)

    #define LGK0() asm volatile("s_waitcnt lgkmcnt(0)" ::: "memory")

    // prologue: B(0) (oldest), A(0), A(1) — pinned order
    G2_STAGEB(myB0, 0);
    SCHED0();
    G2_LOADA(arE, 0);
    SCHED0();
    G2_LOADA(arO, 64);
    SCHED0();

    // steady pairs. Pinned phase order makes the vmcnt queue algebra exact:
    //  even tile t: queue in = {B(t),A(t),A(t+1)}; stage B(t+1); convert A(t)
    //   (implicit wait drains B(t),A(t)); load A(t+2); vmcnt(24) no-op;
    //   compute B(t) [drained].
    //  odd tile t+1: queue in = {A(t+1),B(t+1),A(t+2)}; stage B(t+2); convert
    //   A(t+1) (drains A(t+1) only); load A(t+3); vmcnt(24) drains B(t+1);
    //   compute B(t+1).
    #pragma unroll 1
    for (int t = 0; t < 30; t += 2) {
        // even tile t: reads myB0
        LGK0(); SCHED0();
        G2_STAGEB(myB1, (t + 1) * 64);
        SCHED0();
        G2_CONVERT(arE);                              // A(t)
        SCHED0();
        G2_LOADA(arE, (t + 2) * 64);                  // A(t+2)
        SCHED0();
        asm volatile("s_waitcnt vmcnt(24)" ::: "memory");
        SCHED0();
        G2_COMPUTE(myB0);
        // odd tile t+1: reads myB1
        LGK0(); SCHED0();
        G2_STAGEB(myB0, (t + 2) * 64);
        SCHED0();
        G2_CONVERT(arO);                              // A(t+1)
        SCHED0();
        if (t + 3 < 32) G2_LOADA(arO, (t + 3) * 64);  // A(t+3)
        SCHED0();
        asm volatile("s_waitcnt vmcnt(24)" ::: "memory");
        SCHED0();
        G2_COMPUTE(myB1);
    }
    // peeled last pair t=30,31: queue in = {B(30),A(30),A(31)}
    LGK0(); SCHED0();
    G2_STAGEB(myB1, 31 * 64);                         // B(31)
    SCHED0();
    G2_CONVERT(arE);                                  // A(30): drains B(30),A(30)
    SCHED0();
    asm volatile("s_waitcnt vmcnt(16)" ::: "memory"); // belt: B(30) drained
    SCHED0();
    G2_COMPUTE(myB0);                                 // B(30)
    G2_CONVERT(arO);                                  // A(31)
    SCHED0();
    asm volatile("s_waitcnt vmcnt(0)" ::: "memory");  // drain B(31)
    SCHED0();
    G2_COMPUTE(myB1);                                 // B(31)

    // ---- epilogue: att inline + bias + relu
    float msm[NH], msi[NH];
    #pragma unroll
    for (int h = 0; h < NH; ++h) {
        msm[h] = ms[(b * NH + h) * 2];
        msi[h] = ms[(b * NH + h) * 2 + 1];
    }
    float rowatt[2][4];
    #pragma unroll
    for (int m = 0; m < 2; ++m)
        #pragma unroll
        for (int j = 0; j < 4; ++j) {
            const int row = row0 + w * 32 + m * 16 + (lane >> 4) * 4 + j;
            float a = 0.f;
            #pragma unroll
            for (int h = 0; h < NH; ++h)
                a += expf(e[((size_t)b * NH + h) * NNODE + row] - msm[h]) * msi[h];
            rowatt[m][j] = 0.25f * a;
        }
    #pragma unroll
    for (int n = 0; n < 4; ++n) {
        const int c = col0 + n * 16 + (lane & 15);
        const float bv = bias[c];
        #pragma unroll
        for (int m = 0; m < 2; ++m)
            #pragma unroll
            for (int j = 0; j < 4; ++j) {
                const int row = row0 + w * 32 + m * 16 + (lane >> 4) * 4 + j;
                out[((size_t)b * NNODE + row) * HD + c] =
                    fmaxf(fmaf(acc[m][n][j], rowatt[m][j], bv), 0.f);
            }
    }
}

extern "C" void kernel_launch(void* const* d_in, const int* in_sizes, int n_in,
                              void* d_out, int out_size, void* d_ws, size_t ws_size,
                              hipStream_t stream) {
    const float* features = (const float*)d_in[0];
    const float* adj      = (const float*)d_in[1];
    const float* Wm       = (const float*)d_in[2];
    const float* bias     = (const float*)d_in[3];
    float* out = (float*)d_out;

    ushort_t* WhT_hi = (ushort_t*)d_ws;                          // 8.39 MB
    ushort_t* wt_hi  = WhT_hi + (size_t)BATCH * HD * NNODE;
    ushort_t* wt_lo  = wt_hi + FDIM * HD;
    float* e  = (float*)(wt_lo + FDIM * HD);
    float* ms = e + (size_t)BATCH * NH * NNODE;

    wprep_kernel<<<HD, 256, 0, stream>>>(Wm, wt_hi, wt_lo);
    gemm1_kernel<<<dim3(MROWS / 64, NH), 256, 0, stream>>>(
        features, wt_hi, wt_lo, WhT_hi, e);
    sm_kernel<<<BATCH * NH, 256, 0, stream>>>(e, ms);
    gemm2_kernel<<<512, 256, 0, stream>>>(
        adj, WhT_hi, e, ms, bias, out);
}